// Round 14
// baseline (1459.622 us; speedup 1.0000x reference)
//
#include <hip/hip_runtime.h>

#define N_NODES 50000
#define N_EDGES 800000
#define DIM 128
#define NGRAPH 512
#define ODIM 64
#define VOCAB 500
#define NBKT 391              // ceil(50000/128) coarse dst-buckets (128 nodes each)
#define NB2 128               // edge partitions
#define EPB2 (N_EDGES / NB2)  // 6250

typedef __attribute__((ext_vector_type(8))) short bf16x8;
typedef __attribute__((ext_vector_type(4))) short bf16x4;
typedef __attribute__((ext_vector_type(4))) float f32x4;

__device__ inline unsigned short f2bf(float f) {
  unsigned u = __builtin_bit_cast(unsigned, f);
  return (unsigned short)((u + 0x7fffu + ((u >> 16) & 1u)) >> 16);
}
__device__ inline float bf2f(unsigned short h) {
  unsigned u = ((unsigned)h) << 16;
  return __builtin_bit_cast(float, u);
}

// ---------------------------------------------------------------- prep: emb + weights f32 -> bf16
__global__ __launch_bounds__(256) void prep_kernel(
    const float* __restrict__ emb,
    const float* __restrict__ w1a, const float* __restrict__ w1b,
    const float* __restrict__ w2a, const float* __restrict__ w2b,
    unsigned short* __restrict__ embb, unsigned short* __restrict__ wbf) {
  int u = blockIdx.x * 256 + threadIdx.x;   // one bf16x8 unit (8 elems)
  const float* src;
  unsigned short* dst;
  if (u < VOCAB * 16) {                     // 8000 units of emb
    src = emb + (size_t)u * 8;
    dst = embb + (size_t)u * 8;
  } else {
    int v = u - VOCAB * 16;                 // 4 x 2048 units of weights
    if (v >= 4 * 2048) return;
    int m = v >> 11, loc = v & 2047;
    const float* w = (m == 0) ? w1a : (m == 1) ? w1b : (m == 2) ? w2a : w2b;
    src = w + (size_t)loc * 8;
    dst = wbf + (size_t)v * 8;
  }
  f32x4 a = ((const f32x4*)src)[0], b = ((const f32x4*)src)[1];
  bf16x8 o;
  #pragma unroll
  for (int e = 0; e < 4; ++e) {
    o[e] = (short)f2bf(a[e]);
    o[4 + e] = (short)f2bf(b[e]);
  }
  *(bf16x8*)dst = o;
}

// ---------------------------------------------------------------- CSR-lite build (2 kernels)
// pass 1: per-partition coarse-bucket histogram
__global__ __launch_bounds__(512) void bkt_hist_kernel(
    const int* __restrict__ ei, unsigned* __restrict__ HB) {
  __shared__ unsigned cnt[NBKT];
  int t = threadIdx.x, b = blockIdx.x;
  for (int i = t; i < NBKT; i += 512) cnt[i] = 0;
  __syncthreads();
  int base = b * EPB2;
  for (int i = t; i < EPB2; i += 512)
    atomicAdd(&cnt[(unsigned)ei[N_EDGES + base + i] >> 7], 1u);
  __syncthreads();
  for (int i = t; i < NBKT; i += 512) HB[(size_t)b * NBKT + i] = cnt[i];
}

// pass 2: scatter to coarse buckets; block computes its prefix + bktbase; block 0 stores bktbase
__global__ __launch_bounds__(512) void bkt_scatter_kernel(
    const int* __restrict__ ei, const unsigned* __restrict__ HB,
    unsigned* __restrict__ eb, int* __restrict__ bktbase) {
  __shared__ unsigned cur[NBKT];
  __shared__ unsigned wsum[8];
  int t = threadIdx.x, b = blockIdx.x;
  int lane = t & 63, wid = t >> 6;
  unsigned pre = 0, tot = 0;
  if (t < NBKT) {
    for (int bb = 0; bb < NB2; ++bb) {          // coalesced row-wise reads
      unsigned h = HB[(size_t)bb * NBKT + t];
      pre += (bb < b) ? h : 0u;
      tot += h;
    }
  }
  unsigned s = tot;                              // exclusive scan of tot -> bktbase
  #pragma unroll
  for (int d = 1; d < 64; d <<= 1) {
    unsigned u = __shfl_up(s, d, 64);
    if (lane >= d) s += u;
  }
  if (lane == 63) wsum[wid] = s;
  __syncthreads();
  if (wid == 0) {
    unsigned ws = (lane < 8) ? wsum[lane] : 0u;
    #pragma unroll
    for (int d = 1; d < 8; d <<= 1) {
      unsigned u = __shfl_up(ws, d, 64);
      if (lane >= d) ws += u;
    }
    if (lane < 8) wsum[lane] = ws;
  }
  __syncthreads();
  unsigned base = s - tot + (wid ? wsum[wid - 1] : 0u);
  if (t < NBKT) cur[t] = base + pre;
  if (b == 0) {
    if (t < NBKT) bktbase[t] = (int)base;
    if (t == NBKT - 1) bktbase[NBKT] = (int)(base + tot);  // == N_EDGES
  }
  __syncthreads();
  int ebase = b * EPB2;
  for (int i = t; i < EPB2; i += 512) {
    int sn = ei[ebase + i];
    unsigned d = (unsigned)ei[N_EDGES + ebase + i];
    unsigned pos = atomicAdd(&cur[d >> 7], 1u);
    eb[pos] = ((d & 127u) << 16) | (unsigned)sn;
  }
}

// ---------------------------------------------------------------- bucket aggregation from eb
// One block per bucket (128 nodes). LDS f32 accumulator [128][128] = 64 KB.
// MODE 0: src features = embb[xidx[src]] (conv1). MODE 1: src features = x[src] (conv2).
template <int MODE>
__global__ __launch_bounds__(512) void agg_eb_kernel(
    const unsigned short* __restrict__ feat, const int* __restrict__ xidx,
    const unsigned* __restrict__ eb, const int* __restrict__ bktbase,
    unsigned short* __restrict__ xa) {
  __shared__ float acc[128 * DIM];   // 64 KB
  int t = threadIdx.x, bkt = blockIdx.x;
  int nbase = bkt * 128;

  // init: self features (f32) into acc
  #pragma unroll
  for (int i = 0; i < 4; ++i) {
    int unit = i * 512 + t;          // 0..2047
    int r = unit >> 4, c = unit & 15;
    int node = nbase + r;
    float v[8] = {0.f, 0.f, 0.f, 0.f, 0.f, 0.f, 0.f, 0.f};
    if (node < N_NODES) {
      int sidx = (MODE == 0) ? xidx[node] : node;
      bf16x8 sv = *(const bf16x8*)(feat + (size_t)sidx * DIM + c * 8);
      #pragma unroll
      for (int e = 0; e < 8; ++e) v[e] = bf2f((unsigned short)sv[e]);
    }
    float* ap = &acc[r * DIM + c * 8];
    #pragma unroll
    for (int e = 0; e < 8; ++e) ap[e] = v[e];
  }
  __syncthreads();

  int bs = bktbase[bkt];
  int cnt = bktbase[bkt + 1] - bs;
  int g = t >> 4;        // edge-slot group 0..31
  int c = t & 15;        // 16 lanes per edge, 8 bf16 each
  int i = g;
  for (; i + 96 < cnt; i += 128) {   // 4 edges in flight per group
    unsigned e0 = eb[bs + i], e1 = eb[bs + i + 32];
    unsigned e2 = eb[bs + i + 64], e3 = eb[bs + i + 96];
    int s0 = (MODE == 0) ? xidx[e0 & 0xFFFFu] : (int)(e0 & 0xFFFFu);
    int s1 = (MODE == 0) ? xidx[e1 & 0xFFFFu] : (int)(e1 & 0xFFFFu);
    int s2 = (MODE == 0) ? xidx[e2 & 0xFFFFu] : (int)(e2 & 0xFFFFu);
    int s3 = (MODE == 0) ? xidx[e3 & 0xFFFFu] : (int)(e3 & 0xFFFFu);
    bf16x8 w0 = *(const bf16x8*)(feat + (size_t)s0 * DIM + c * 8);
    bf16x8 w1 = *(const bf16x8*)(feat + (size_t)s1 * DIM + c * 8);
    bf16x8 w2 = *(const bf16x8*)(feat + (size_t)s2 * DIM + c * 8);
    bf16x8 w3 = *(const bf16x8*)(feat + (size_t)s3 * DIM + c * 8);
    float* a0 = &acc[(int)(e0 >> 16) * DIM + c * 8];
    float* a1 = &acc[(int)(e1 >> 16) * DIM + c * 8];
    float* a2 = &acc[(int)(e2 >> 16) * DIM + c * 8];
    float* a3 = &acc[(int)(e3 >> 16) * DIM + c * 8];
    #pragma unroll
    for (int e = 0; e < 8; ++e) atomicAdd(&a0[e], bf2f((unsigned short)w0[e]));
    #pragma unroll
    for (int e = 0; e < 8; ++e) atomicAdd(&a1[e], bf2f((unsigned short)w1[e]));
    #pragma unroll
    for (int e = 0; e < 8; ++e) atomicAdd(&a2[e], bf2f((unsigned short)w2[e]));
    #pragma unroll
    for (int e = 0; e < 8; ++e) atomicAdd(&a3[e], bf2f((unsigned short)w3[e]));
  }
  for (; i < cnt; i += 32) {
    unsigned e0 = eb[bs + i];
    int s0 = (MODE == 0) ? xidx[e0 & 0xFFFFu] : (int)(e0 & 0xFFFFu);
    bf16x8 w0 = *(const bf16x8*)(feat + (size_t)s0 * DIM + c * 8);
    float* a0 = &acc[(int)(e0 >> 16) * DIM + c * 8];
    #pragma unroll
    for (int e = 0; e < 8; ++e) atomicAdd(&a0[e], bf2f((unsigned short)w0[e]));
  }
  __syncthreads();

  // write back bf16 (coalesced)
  #pragma unroll
  for (int ii = 0; ii < 4; ++ii) {
    int unit = ii * 512 + t;
    int r = unit >> 4, cc = unit & 15;
    int node = nbase + r;
    if (node < N_NODES) {
      const float* ap = &acc[r * DIM + cc * 8];
      bf16x8 o;
      #pragma unroll
      for (int e = 0; e < 8; ++e) o[e] = (short)f2bf(ap[e]);
      *(bf16x8*)(xa + (size_t)node * DIM + cc * 8) = o;
    }
  }
}

// ---------------------------------------------------------------- MLP: 256 thr, 128 nodes (2 halves)
__global__ __launch_bounds__(256) void mlp_mfma_kernel(
    const unsigned short* __restrict__ xa,
    const unsigned short* __restrict__ wabf, const float* __restrict__ ba,
    const unsigned short* __restrict__ wbbf, const float* __restrict__ bb,
    unsigned short* __restrict__ xout) {
  __shared__ short Xs[64 * 128];   // 16 KB, 16B-chunk XOR swizzle (chunk ^= row&7)
  __shared__ short Hs[64 * 128];   // 16 KB
  int t = threadIdx.x;
  int lane = t & 63;
  int w = t >> 6;
  int jq = w * 32;
  int l15 = lane & 15;
  int lg = lane >> 4;

  bf16x8 waf[2][4], wbf[2][4];
  #pragma unroll
  for (int jm = 0; jm < 2; ++jm) {
    int jrow = jq + jm * 16 + l15;
    #pragma unroll
    for (int ks = 0; ks < 4; ++ks) {
      int k0 = ks * 32 + lg * 8;
      waf[jm][ks] = *(const bf16x8*)(wabf + (size_t)jrow * DIM + k0);
      wbf[jm][ks] = *(const bf16x8*)(wbbf + (size_t)jrow * DIM + k0);
    }
  }
  f32x4 ba_r[2], bb_r[2];
  #pragma unroll
  for (int jm = 0; jm < 2; ++jm) {
    ba_r[jm] = *(const f32x4*)(ba + jq + jm * 16 + lg * 4);
    bb_r[jm] = *(const f32x4*)(bb + jq + jm * 16 + lg * 4);
  }

  for (int half = 0; half < 2; ++half) {
    int nbase = blockIdx.x * 128 + half * 64;

    {
      int r = t >> 2;
      int cb = (t & 3) * 4;
      int node = nbase + r;
      #pragma unroll
      for (int i = 0; i < 4; ++i) {
        int chunk = cb + i;
        bf16x8 v = {0, 0, 0, 0, 0, 0, 0, 0};
        if (node < N_NODES)
          v = *(const bf16x8*)(xa + (size_t)node * DIM + chunk * 8);
        *(bf16x8*)&Xs[r * 128 + ((chunk ^ (r & 7)) << 3)] = v;
      }
    }
    __syncthreads();

    #pragma unroll
    for (int nt = 0; nt < 4; ++nt) {
      int rrow = nt * 16 + l15;
      bf16x8 xf[4];
      #pragma unroll
      for (int ks = 0; ks < 4; ++ks) {
        int chunk = ks * 4 + lg;
        xf[ks] = *(const bf16x8*)&Xs[rrow * 128 + ((chunk ^ (rrow & 7)) << 3)];
      }
      #pragma unroll
      for (int jm = 0; jm < 2; ++jm) {
        f32x4 acc = ba_r[jm];
        #pragma unroll
        for (int ks = 0; ks < 4; ++ks)
          acc = __builtin_amdgcn_mfma_f32_16x16x32_bf16(waf[jm][ks], xf[ks], acc, 0, 0, 0);
        int hnode = nt * 16 + l15;
        int cbase = jq + jm * 16 + lg * 4;
        unsigned p0 = (unsigned)f2bf(fmaxf(acc[0], 0.f)) |
                      ((unsigned)f2bf(fmaxf(acc[1], 0.f)) << 16);
        unsigned p1 = (unsigned)f2bf(fmaxf(acc[2], 0.f)) |
                      ((unsigned)f2bf(fmaxf(acc[3], 0.f)) << 16);
        unsigned idx = hnode * 128 + (((cbase >> 3) ^ (hnode & 7)) << 3) + (cbase & 7);
        *(uint2*)&Hs[idx] = make_uint2(p0, p1);
      }
    }
    __syncthreads();

    #pragma unroll
    for (int nt = 0; nt < 4; ++nt) {
      int rrow = nt * 16 + l15;
      bf16x8 hf[4];
      #pragma unroll
      for (int ks = 0; ks < 4; ++ks) {
        int chunk = ks * 4 + lg;
        hf[ks] = *(const bf16x8*)&Hs[rrow * 128 + ((chunk ^ (rrow & 7)) << 3)];
      }
      #pragma unroll
      for (int jm = 0; jm < 2; ++jm) {
        f32x4 acc = bb_r[jm];
        #pragma unroll
        for (int ks = 0; ks < 4; ++ks)
          acc = __builtin_amdgcn_mfma_f32_16x16x32_bf16(wbf[jm][ks], hf[ks], acc, 0, 0, 0);
        int node = nbase + nt * 16 + l15;
        if (node < N_NODES) {
          bf16x4 o;
          #pragma unroll
          for (int e = 0; e < 4; ++e) o[e] = (short)f2bf(fmaxf(acc[e], 0.f));
          *(bf16x4*)(xout + (size_t)node * DIM + jq + jm * 16 + lg * 4) = o;
        }
      }
    }
    __syncthreads();   // protect Xs/Hs before next half
  }
}

// ---------------------------------------------------------------- mean-pool + FC (row-parallel)
#define PP 132
__global__ __launch_bounds__(256) void pool_fc_kernel(
    const unsigned short* __restrict__ x, const int* __restrict__ batch,
    const float* __restrict__ fcw, const float* __restrict__ fcb,
    float* __restrict__ out) {
  int g = blockIdx.x, t = threadIdx.x;
  __shared__ float part[16 * PP];
  __shared__ float pooled[DIM];
  __shared__ int sbound[2];
  if (t < 2) {
    int target = g + t;
    int lo = 0, hi = N_NODES;
    while (lo < hi) {
      int m = (lo + hi) >> 1;
      if (batch[m] < target) lo = m + 1; else hi = m;
    }
    sbound[t] = lo;
  }
  __syncthreads();
  int lo = sbound[0], hi = sbound[1];
  int r = t >> 4, c = t & 15;
  float acc[8] = {0.f, 0.f, 0.f, 0.f, 0.f, 0.f, 0.f, 0.f};
  for (int nn = lo + r; nn < hi; nn += 16) {
    bf16x8 v = *(const bf16x8*)(x + (size_t)nn * DIM + c * 8);
    #pragma unroll
    for (int e = 0; e < 8; ++e) acc[e] += bf2f((unsigned short)v[e]);
  }
  #pragma unroll
  for (int e = 0; e < 8; ++e) part[r * PP + c * 8 + e] = acc[e];
  __syncthreads();
  if (t < DIM) {
    float s = 0.f;
    #pragma unroll
    for (int rr = 0; rr < 16; ++rr) s += part[rr * PP + t];
    pooled[t] = s / fmaxf((float)(hi - lo), 1.0f);
  }
  __syncthreads();
  if (t < ODIM) {
    float a = fcb[t];
    const float* wr = fcw + (size_t)t * DIM;
    #pragma unroll 8
    for (int h = 0; h < DIM; ++h) a += pooled[h] * wr[h];
    out[(size_t)g * ODIM + t] = a;
  }
}

// ---------------------------------------------------------------- launch
extern "C" void kernel_launch(void* const* d_in, const int* in_sizes, int n_in,
                              void* d_out, int out_size, void* d_ws, size_t ws_size,
                              hipStream_t stream) {
  const float* emb  = (const float*)d_in[0];
  const float* w1a  = (const float*)d_in[1];
  const float* b1a  = (const float*)d_in[2];
  const float* w1b  = (const float*)d_in[3];
  const float* b1b  = (const float*)d_in[4];
  const float* w2a  = (const float*)d_in[5];
  const float* b2a  = (const float*)d_in[6];
  const float* w2b  = (const float*)d_in[7];
  const float* b2b  = (const float*)d_in[8];
  const float* fcw  = (const float*)d_in[9];
  const float* fcb  = (const float*)d_in[10];
  const int*   xidx = (const int*)d_in[11];
  const int*   ei   = (const int*)d_in[12];
  const int*   batch= (const int*)d_in[13];
  float* out = (float*)d_out;

  size_t featb = (size_t)N_NODES * DIM * sizeof(unsigned short);  // 12.8 MB
  char* ws = (char*)d_ws;
  unsigned short* B1 = (unsigned short*)ws;             // agg buffer
  unsigned short* B2 = (unsigned short*)(ws + featb);   // conv out
  char* p = ws + 2 * featb;
  unsigned short* embb = (unsigned short*)p;  p += (VOCAB * DIM * 2 + 15) / 16 * 16;
  unsigned short* wbf  = (unsigned short*)p;  p += (4 * DIM * DIM * 2 + 15) / 16 * 16;  // 128 KB
  int* bktbase = (int*)p;   p += ((NBKT + 1) * 4 + 15) / 16 * 16;
  unsigned* HB  = (unsigned*)p;  p += (size_t)NB2 * NBKT * 4;    // 200 KB
  unsigned* eb  = (unsigned*)p;  // 3.2 MB

  const unsigned short* w1abf = wbf;
  const unsigned short* w1bbf = wbf + DIM * DIM;
  const unsigned short* w2abf = wbf + 2 * DIM * DIM;
  const unsigned short* w2bbf = wbf + 3 * DIM * DIM;

  prep_kernel<<<(VOCAB * 16 + 4 * 2048 + 255) / 256, 256, 0, stream>>>(
      emb, w1a, w1b, w2a, w2b, embb, wbf);

  // bucket build: hist -> scatter (stores bktbase); no sort needed
  bkt_hist_kernel<<<NB2, 512, 0, stream>>>(ei, HB);
  bkt_scatter_kernel<<<NB2, 512, 0, stream>>>(ei, HB, eb, bktbase);

  // conv1: bucket-aggregate from L2-resident emb table, then MLP
  agg_eb_kernel<0><<<NBKT, 512, 0, stream>>>(embb, xidx, eb, bktbase, B1);
  mlp_mfma_kernel<<<(N_NODES + 127) / 128, 256, 0, stream>>>(B1, w1abf, b1a, w1bbf, b1b, B2);

  // conv2: bucket-aggregate from node features, then MLP
  agg_eb_kernel<1><<<NBKT, 512, 0, stream>>>(B2, xidx, eb, bktbase, B1);
  mlp_mfma_kernel<<<(N_NODES + 127) / 128, 256, 0, stream>>>(B1, w2abf, b2a, w2bbf, b2b, B2);

  pool_fc_kernel<<<NGRAPH, 256, 0, stream>>>(B2, batch, fcw, fcb, out);
}

// Round 15
// 128.055 us; speedup vs baseline: 11.3984x; 11.3984x over previous
//
#include <hip/hip_runtime.h>

#define N_NODES 50000
#define N_EDGES 800000
#define DIM 128
#define NGRAPH 512
#define ODIM 64
#define VOCAB 500
#define NBKT 391              // ceil(50000/128) coarse dst-buckets (128 nodes each)
#define NB2 128               // edge partitions
#define EPB2 (N_EDGES / NB2)  // 6250
#define CAP 4096              // max edges per bucket staged in LDS (mean 2046)

typedef __attribute__((ext_vector_type(8))) short bf16x8;
typedef __attribute__((ext_vector_type(4))) short bf16x4;
typedef __attribute__((ext_vector_type(4))) float f32x4;

__device__ inline unsigned short f2bf(float f) {
  unsigned u = __builtin_bit_cast(unsigned, f);
  return (unsigned short)((u + 0x7fffu + ((u >> 16) & 1u)) >> 16);
}
__device__ inline float bf2f(unsigned short h) {
  unsigned u = ((unsigned)h) << 16;
  return __builtin_bit_cast(float, u);
}

// ---------------------------------------------------------------- prep: emb + weights f32 -> bf16
__global__ __launch_bounds__(256) void prep_kernel(
    const float* __restrict__ emb,
    const float* __restrict__ w1a, const float* __restrict__ w1b,
    const float* __restrict__ w2a, const float* __restrict__ w2b,
    unsigned short* __restrict__ embb, unsigned short* __restrict__ wbf) {
  int u = blockIdx.x * 256 + threadIdx.x;   // one bf16x8 unit (8 elems)
  const float* src;
  unsigned short* dst;
  if (u < VOCAB * 16) {                     // 8000 units of emb
    src = emb + (size_t)u * 8;
    dst = embb + (size_t)u * 8;
  } else {
    int v = u - VOCAB * 16;                 // 4 x 2048 units of weights
    if (v >= 4 * 2048) return;
    int m = v >> 11, loc = v & 2047;
    const float* w = (m == 0) ? w1a : (m == 1) ? w1b : (m == 2) ? w2a : w2b;
    src = w + (size_t)loc * 8;
    dst = wbf + (size_t)v * 8;
  }
  f32x4 a = ((const f32x4*)src)[0], b = ((const f32x4*)src)[1];
  bf16x8 o;
  #pragma unroll
  for (int e = 0; e < 4; ++e) {
    o[e] = (short)f2bf(a[e]);
    o[4 + e] = (short)f2bf(b[e]);
  }
  *(bf16x8*)dst = o;
}

// ---------------------------------------------------------------- CSR build (3 kernels)
// pass 1: per-partition coarse-bucket histogram
__global__ __launch_bounds__(512) void bkt_hist_kernel(
    const int* __restrict__ ei, unsigned* __restrict__ HB) {
  __shared__ unsigned cnt[NBKT];
  int t = threadIdx.x, b = blockIdx.x;
  for (int i = t; i < NBKT; i += 512) cnt[i] = 0;
  __syncthreads();
  int base = b * EPB2;
  for (int i = t; i < EPB2; i += 512)
    atomicAdd(&cnt[(unsigned)ei[N_EDGES + base + i] >> 7], 1u);
  __syncthreads();
  for (int i = t; i < NBKT; i += 512) HB[(size_t)b * NBKT + i] = cnt[i];
}

// pass 2: scatter to coarse buckets; block computes its prefix + bktbase; block 0 stores bktbase
__global__ __launch_bounds__(512) void bkt_scatter_kernel(
    const int* __restrict__ ei, const unsigned* __restrict__ HB,
    unsigned* __restrict__ eb, int* __restrict__ bktbase) {
  __shared__ unsigned cur[NBKT];
  __shared__ unsigned wsum[8];
  int t = threadIdx.x, b = blockIdx.x;
  int lane = t & 63, wid = t >> 6;
  unsigned pre = 0, tot = 0;
  if (t < NBKT) {
    for (int bb = 0; bb < NB2; ++bb) {          // coalesced row-wise reads
      unsigned h = HB[(size_t)bb * NBKT + t];
      pre += (bb < b) ? h : 0u;
      tot += h;
    }
  }
  unsigned s = tot;                              // exclusive scan of tot -> bktbase
  #pragma unroll
  for (int d = 1; d < 64; d <<= 1) {
    unsigned u = __shfl_up(s, d, 64);
    if (lane >= d) s += u;
  }
  if (lane == 63) wsum[wid] = s;
  __syncthreads();
  if (wid == 0) {
    unsigned ws = (lane < 8) ? wsum[lane] : 0u;
    #pragma unroll
    for (int d = 1; d < 8; d <<= 1) {
      unsigned u = __shfl_up(ws, d, 64);
      if (lane >= d) ws += u;
    }
    if (lane < 8) wsum[lane] = ws;
  }
  __syncthreads();
  unsigned base = s - tot + (wid ? wsum[wid - 1] : 0u);
  if (t < NBKT) cur[t] = base + pre;
  if (b == 0) {
    if (t < NBKT) bktbase[t] = (int)base;
    if (t == NBKT - 1) bktbase[NBKT] = (int)(base + tot);  // == N_EDGES
  }
  __syncthreads();
  int ebase = b * EPB2;
  for (int i = t; i < EPB2; i += 512) {
    int sn = ei[ebase + i];
    unsigned d = (unsigned)ei[N_EDGES + ebase + i];
    unsigned pos = atomicAdd(&cur[d >> 7], 1u);
    eb[pos] = ((d & 127u) << 16) | (unsigned)sn;
  }
}

// pass 3: per-bucket LDS counting sort -> coalesced srt + row (bktbase read, not recomputed)
__global__ __launch_bounds__(512) void sort_bucket_kernel(
    const unsigned* __restrict__ eb, const int* __restrict__ bktbase,
    int* __restrict__ srt, int* __restrict__ row) {
  __shared__ unsigned stage[CAP];        // 16 KB
  __shared__ unsigned short sorted[CAP]; // 8 KB
  __shared__ unsigned hist[128], cur[128];
  __shared__ unsigned wtot;
  int t = threadIdx.x, bkt = blockIdx.x;
  int bs = bktbase[bkt], be = bktbase[bkt + 1];
  int cnt = be - bs;
  if (cnt > CAP) cnt = CAP;   // statistically impossible; guards LDS
  if (t < 128) hist[t] = 0;
  if (bkt == 0 && t == 0) row[N_NODES] = N_EDGES;
  __syncthreads();
  for (int i = t; i < cnt; i += 512) {
    unsigned e = eb[bs + i];
    stage[i] = e;
    atomicAdd(&hist[e >> 16], 1u);
  }
  __syncthreads();
  if (t < 128) {                         // exclusive scan of 128 node counters
    int lane = t & 63;
    unsigned v = hist[t], ss = v;
    #pragma unroll
    for (int d = 1; d < 64; d <<= 1) {
      unsigned u = __shfl_up(ss, d, 64);
      if (lane >= d) ss += u;
    }
    if (t == 63) wtot = ss;
    cur[t] = ss - v;                     // wave-local exclusive
  }
  __syncthreads();
  if (t < 128) {
    unsigned e0 = cur[t] + (t >= 64 ? wtot : 0u);
    cur[t] = e0;
    int n = bkt * 128 + t;
    if (n < N_NODES) row[n] = bs + (int)e0;
  }
  __syncthreads();
  for (int i = t; i < cnt; i += 512) {
    unsigned e = stage[i];
    unsigned r = atomicAdd(&cur[e >> 16], 1u);
    sorted[r] = (unsigned short)(e & 0xFFFFu);
  }
  __syncthreads();
  for (int i = t; i < cnt; i += 512) srt[bs + i] = (int)sorted[i];
}

// ---------------------------------------------------------------- agg (conv1): from emb table
// 16 lanes/node, bf16x8 (16 B) per lane; 16 nodes per 256-block; 8-deep gather unroll
__global__ __launch_bounds__(256) void agg_emb_kernel(
    const unsigned short* __restrict__ embb, const int* __restrict__ xidx,
    const int* __restrict__ row, const int* __restrict__ srt,
    unsigned short* __restrict__ xa) {
  int n = blockIdx.x * 16 + (threadIdx.x >> 4);
  int c = threadIdx.x & 15;
  int lo = row[n], hi = row[n + 1];
  bf16x8 sv = *(const bf16x8*)(embb + (size_t)xidx[n] * DIM + c * 8);
  float a[8];
  #pragma unroll
  for (int e = 0; e < 8; ++e) a[e] = bf2f((unsigned short)sv[e]);
  int k = lo;
  for (; k + 8 <= hi; k += 8) {
    bf16x8 w[8];
    #pragma unroll
    for (int q = 0; q < 8; ++q)
      w[q] = *(const bf16x8*)(embb + (size_t)xidx[srt[k + q]] * DIM + c * 8);
    #pragma unroll
    for (int q = 0; q < 8; ++q)
      #pragma unroll
      for (int e = 0; e < 8; ++e) a[e] += bf2f((unsigned short)w[q][e]);
  }
  for (; k + 2 <= hi; k += 2) {
    bf16x8 w0 = *(const bf16x8*)(embb + (size_t)xidx[srt[k]] * DIM + c * 8);
    bf16x8 w1 = *(const bf16x8*)(embb + (size_t)xidx[srt[k + 1]] * DIM + c * 8);
    #pragma unroll
    for (int e = 0; e < 8; ++e)
      a[e] += bf2f((unsigned short)w0[e]) + bf2f((unsigned short)w1[e]);
  }
  if (k < hi) {
    bf16x8 w = *(const bf16x8*)(embb + (size_t)xidx[srt[k]] * DIM + c * 8);
    #pragma unroll
    for (int e = 0; e < 8; ++e) a[e] += bf2f((unsigned short)w[e]);
  }
  bf16x8 o;
  #pragma unroll
  for (int e = 0; e < 8; ++e) o[e] = (short)f2bf(a[e]);
  *(bf16x8*)(xa + (size_t)n * DIM + c * 8) = o;
}

// ---------------------------------------------------------------- agg (conv2): from node features
__global__ __launch_bounds__(256) void agg_x_kernel(
    const unsigned short* __restrict__ x, const int* __restrict__ row,
    const int* __restrict__ srt, unsigned short* __restrict__ xa) {
  int n = blockIdx.x * 16 + (threadIdx.x >> 4);
  int c = threadIdx.x & 15;
  int lo = row[n], hi = row[n + 1];
  bf16x8 sv = *(const bf16x8*)(x + (size_t)n * DIM + c * 8);
  float a[8];
  #pragma unroll
  for (int e = 0; e < 8; ++e) a[e] = bf2f((unsigned short)sv[e]);
  int k = lo;
  for (; k + 8 <= hi; k += 8) {
    bf16x8 w[8];
    #pragma unroll
    for (int q = 0; q < 8; ++q)
      w[q] = *(const bf16x8*)(x + (size_t)srt[k + q] * DIM + c * 8);
    #pragma unroll
    for (int q = 0; q < 8; ++q)
      #pragma unroll
      for (int e = 0; e < 8; ++e) a[e] += bf2f((unsigned short)w[q][e]);
  }
  for (; k + 2 <= hi; k += 2) {
    bf16x8 w0 = *(const bf16x8*)(x + (size_t)srt[k] * DIM + c * 8);
    bf16x8 w1 = *(const bf16x8*)(x + (size_t)srt[k + 1] * DIM + c * 8);
    #pragma unroll
    for (int e = 0; e < 8; ++e)
      a[e] += bf2f((unsigned short)w0[e]) + bf2f((unsigned short)w1[e]);
  }
  if (k < hi) {
    bf16x8 w = *(const bf16x8*)(x + (size_t)srt[k] * DIM + c * 8);
    #pragma unroll
    for (int e = 0; e < 8; ++e) a[e] += bf2f((unsigned short)w[e]);
  }
  bf16x8 o;
  #pragma unroll
  for (int e = 0; e < 8; ++e) o[e] = (short)f2bf(a[e]);
  *(bf16x8*)(xa + (size_t)n * DIM + c * 8) = o;
}

// ---------------------------------------------------------------- MLP: 256 thr, 128 nodes (2 halves)
__global__ __launch_bounds__(256) void mlp_mfma_kernel(
    const unsigned short* __restrict__ xa,
    const unsigned short* __restrict__ wabf, const float* __restrict__ ba,
    const unsigned short* __restrict__ wbbf, const float* __restrict__ bb,
    unsigned short* __restrict__ xout) {
  __shared__ short Xs[64 * 128];   // 16 KB, 16B-chunk XOR swizzle (chunk ^= row&7)
  __shared__ short Hs[64 * 128];   // 16 KB
  int t = threadIdx.x;
  int lane = t & 63;
  int w = t >> 6;
  int jq = w * 32;
  int l15 = lane & 15;
  int lg = lane >> 4;

  bf16x8 waf[2][4], wbf[2][4];
  #pragma unroll
  for (int jm = 0; jm < 2; ++jm) {
    int jrow = jq + jm * 16 + l15;
    #pragma unroll
    for (int ks = 0; ks < 4; ++ks) {
      int k0 = ks * 32 + lg * 8;
      waf[jm][ks] = *(const bf16x8*)(wabf + (size_t)jrow * DIM + k0);
      wbf[jm][ks] = *(const bf16x8*)(wbbf + (size_t)jrow * DIM + k0);
    }
  }
  f32x4 ba_r[2], bb_r[2];
  #pragma unroll
  for (int jm = 0; jm < 2; ++jm) {
    ba_r[jm] = *(const f32x4*)(ba + jq + jm * 16 + lg * 4);
    bb_r[jm] = *(const f32x4*)(bb + jq + jm * 16 + lg * 4);
  }

  for (int half = 0; half < 2; ++half) {
    int nbase = blockIdx.x * 128 + half * 64;

    {
      int r = t >> 2;
      int cb = (t & 3) * 4;
      int node = nbase + r;
      #pragma unroll
      for (int i = 0; i < 4; ++i) {
        int chunk = cb + i;
        bf16x8 v = {0, 0, 0, 0, 0, 0, 0, 0};
        if (node < N_NODES)
          v = *(const bf16x8*)(xa + (size_t)node * DIM + chunk * 8);
        *(bf16x8*)&Xs[r * 128 + ((chunk ^ (r & 7)) << 3)] = v;
      }
    }
    __syncthreads();

    #pragma unroll
    for (int nt = 0; nt < 4; ++nt) {
      int rrow = nt * 16 + l15;
      bf16x8 xf[4];
      #pragma unroll
      for (int ks = 0; ks < 4; ++ks) {
        int chunk = ks * 4 + lg;
        xf[ks] = *(const bf16x8*)&Xs[rrow * 128 + ((chunk ^ (rrow & 7)) << 3)];
      }
      #pragma unroll
      for (int jm = 0; jm < 2; ++jm) {
        f32x4 acc = ba_r[jm];
        #pragma unroll
        for (int ks = 0; ks < 4; ++ks)
          acc = __builtin_amdgcn_mfma_f32_16x16x32_bf16(waf[jm][ks], xf[ks], acc, 0, 0, 0);
        int hnode = nt * 16 + l15;
        int cbase = jq + jm * 16 + lg * 4;
        unsigned p0 = (unsigned)f2bf(fmaxf(acc[0], 0.f)) |
                      ((unsigned)f2bf(fmaxf(acc[1], 0.f)) << 16);
        unsigned p1 = (unsigned)f2bf(fmaxf(acc[2], 0.f)) |
                      ((unsigned)f2bf(fmaxf(acc[3], 0.f)) << 16);
        unsigned idx = hnode * 128 + (((cbase >> 3) ^ (hnode & 7)) << 3) + (cbase & 7);
        *(uint2*)&Hs[idx] = make_uint2(p0, p1);
      }
    }
    __syncthreads();

    #pragma unroll
    for (int nt = 0; nt < 4; ++nt) {
      int rrow = nt * 16 + l15;
      bf16x8 hf[4];
      #pragma unroll
      for (int ks = 0; ks < 4; ++ks) {
        int chunk = ks * 4 + lg;
        hf[ks] = *(const bf16x8*)&Hs[rrow * 128 + ((chunk ^ (rrow & 7)) << 3)];
      }
      #pragma unroll
      for (int jm = 0; jm < 2; ++jm) {
        f32x4 acc = bb_r[jm];
        #pragma unroll
        for (int ks = 0; ks < 4; ++ks)
          acc = __builtin_amdgcn_mfma_f32_16x16x32_bf16(wbf[jm][ks], hf[ks], acc, 0, 0, 0);
        int node = nbase + nt * 16 + l15;
        if (node < N_NODES) {
          bf16x4 o;
          #pragma unroll
          for (int e = 0; e < 4; ++e) o[e] = (short)f2bf(fmaxf(acc[e], 0.f));
          *(bf16x4*)(xout + (size_t)node * DIM + jq + jm * 16 + lg * 4) = o;
        }
      }
    }
    __syncthreads();   // protect Xs/Hs before next half
  }
}

// ---------------------------------------------------------------- mean-pool + FC (row-parallel)
#define PP 132
__global__ __launch_bounds__(256) void pool_fc_kernel(
    const unsigned short* __restrict__ x, const int* __restrict__ batch,
    const float* __restrict__ fcw, const float* __restrict__ fcb,
    float* __restrict__ out) {
  int g = blockIdx.x, t = threadIdx.x;
  __shared__ float part[16 * PP];
  __shared__ float pooled[DIM];
  __shared__ int sbound[2];
  if (t < 2) {
    int target = g + t;
    int lo = 0, hi = N_NODES;
    while (lo < hi) {
      int m = (lo + hi) >> 1;
      if (batch[m] < target) lo = m + 1; else hi = m;
    }
    sbound[t] = lo;
  }
  __syncthreads();
  int lo = sbound[0], hi = sbound[1];
  int r = t >> 4, c = t & 15;
  float acc[8] = {0.f, 0.f, 0.f, 0.f, 0.f, 0.f, 0.f, 0.f};
  for (int nn = lo + r; nn < hi; nn += 16) {
    bf16x8 v = *(const bf16x8*)(x + (size_t)nn * DIM + c * 8);
    #pragma unroll
    for (int e = 0; e < 8; ++e) acc[e] += bf2f((unsigned short)v[e]);
  }
  #pragma unroll
  for (int e = 0; e < 8; ++e) part[r * PP + c * 8 + e] = acc[e];
  __syncthreads();
  if (t < DIM) {
    float s = 0.f;
    #pragma unroll
    for (int rr = 0; rr < 16; ++rr) s += part[rr * PP + t];
    pooled[t] = s / fmaxf((float)(hi - lo), 1.0f);
  }
  __syncthreads();
  if (t < ODIM) {
    float a = fcb[t];
    const float* wr = fcw + (size_t)t * DIM;
    #pragma unroll 8
    for (int h = 0; h < DIM; ++h) a += pooled[h] * wr[h];
    out[(size_t)g * ODIM + t] = a;
  }
}

// ---------------------------------------------------------------- launch
extern "C" void kernel_launch(void* const* d_in, const int* in_sizes, int n_in,
                              void* d_out, int out_size, void* d_ws, size_t ws_size,
                              hipStream_t stream) {
  const float* emb  = (const float*)d_in[0];
  const float* w1a  = (const float*)d_in[1];
  const float* b1a  = (const float*)d_in[2];
  const float* w1b  = (const float*)d_in[3];
  const float* b1b  = (const float*)d_in[4];
  const float* w2a  = (const float*)d_in[5];
  const float* b2a  = (const float*)d_in[6];
  const float* w2b  = (const float*)d_in[7];
  const float* b2b  = (const float*)d_in[8];
  const float* fcw  = (const float*)d_in[9];
  const float* fcb  = (const float*)d_in[10];
  const int*   xidx = (const int*)d_in[11];
  const int*   ei   = (const int*)d_in[12];
  const int*   batch= (const int*)d_in[13];
  float* out = (float*)d_out;

  size_t featb = (size_t)N_NODES * DIM * sizeof(unsigned short);  // 12.8 MB
  char* ws = (char*)d_ws;
  unsigned short* B1 = (unsigned short*)ws;             // agg buffer
  unsigned short* B2 = (unsigned short*)(ws + featb);   // conv out
  char* p = ws + 2 * featb;
  unsigned short* embb = (unsigned short*)p;  p += (VOCAB * DIM * 2 + 15) / 16 * 16;
  unsigned short* wbf  = (unsigned short*)p;  p += (4 * DIM * DIM * 2 + 15) / 16 * 16;  // 128 KB
  int* row  = (int*)p;      p += ((N_NODES + 1) * 4 + 15) / 16 * 16;
  int* bktbase = (int*)p;   p += ((NBKT + 1) * 4 + 15) / 16 * 16;
  unsigned* HB  = (unsigned*)p;  p += (size_t)NB2 * NBKT * 4;    // 200 KB
  unsigned* eb  = (unsigned*)p;  p += (size_t)N_EDGES * 4;       // 3.2 MB
  int* srt  = (int*)p;      // N_EDGES ints (3.2 MB)

  const unsigned short* w1abf = wbf;
  const unsigned short* w1bbf = wbf + DIM * DIM;
  const unsigned short* w2abf = wbf + 2 * DIM * DIM;
  const unsigned short* w2bbf = wbf + 3 * DIM * DIM;

  prep_kernel<<<(VOCAB * 16 + 4 * 2048 + 255) / 256, 256, 0, stream>>>(
      emb, w1a, w1b, w2a, w2b, embb, wbf);

  // CSR build: hist -> bucket scatter (stores bktbase) -> per-bucket counting sort
  bkt_hist_kernel<<<NB2, 512, 0, stream>>>(ei, HB);
  bkt_scatter_kernel<<<NB2, 512, 0, stream>>>(ei, HB, eb, bktbase);
  sort_bucket_kernel<<<NBKT, 512, 0, stream>>>(eb, bktbase, srt, row);

  // conv1: gather from L2-resident emb table, then MLP
  agg_emb_kernel<<<N_NODES / 16, 256, 0, stream>>>(embb, xidx, row, srt, B1);
  mlp_mfma_kernel<<<(N_NODES + 127) / 128, 256, 0, stream>>>(B1, w1abf, b1a, w1bbf, b1b, B2);

  // conv2: gather from node features, then MLP
  agg_x_kernel<<<N_NODES / 16, 256, 0, stream>>>(B2, row, srt, B1);
  mlp_mfma_kernel<<<(N_NODES + 127) / 128, 256, 0, stream>>>(B1, w2abf, b2a, w2bbf, b2b, B2);

  pool_fc_kernel<<<NGRAPH, 256, 0, stream>>>(B2, batch, fcw, fcb, out);
}

// Round 16
// 120.627 us; speedup vs baseline: 12.1003x; 1.0616x over previous
//
#include <hip/hip_runtime.h>

#define N_NODES 50000
#define N_EDGES 800000
#define DIM 128
#define NGRAPH 512
#define ODIM 64
#define VOCAB 500
#define NBKT 391              // ceil(50000/128) coarse dst-buckets (128 nodes each)
#define NB2 128               // edge partitions
#define EPB2 (N_EDGES / NB2)  // 6250
#define CAP 4096              // fixed capacity per bucket (mean 2046, 45 sigma margin)

typedef __attribute__((ext_vector_type(8))) short bf16x8;
typedef __attribute__((ext_vector_type(4))) short bf16x4;
typedef __attribute__((ext_vector_type(4))) float f32x4;

__device__ inline unsigned short f2bf(float f) {
  unsigned u = __builtin_bit_cast(unsigned, f);
  return (unsigned short)((u + 0x7fffu + ((u >> 16) & 1u)) >> 16);
}
__device__ inline float bf2f(unsigned short h) {
  unsigned u = ((unsigned)h) << 16;
  return __builtin_bit_cast(float, u);
}

// ---------------------------------------------------------------- prep: emb + weights f32 -> bf16; zero gcnt
__global__ __launch_bounds__(256) void prep_kernel(
    const float* __restrict__ emb,
    const float* __restrict__ w1a, const float* __restrict__ w1b,
    const float* __restrict__ w2a, const float* __restrict__ w2b,
    unsigned short* __restrict__ embb, unsigned short* __restrict__ wbf,
    int* __restrict__ gcnt) {
  int u = blockIdx.x * 256 + threadIdx.x;   // one bf16x8 unit (8 elems)
  if (u < NBKT) gcnt[u] = 0;
  const float* src;
  unsigned short* dst;
  if (u < VOCAB * 16) {                     // 8000 units of emb
    src = emb + (size_t)u * 8;
    dst = embb + (size_t)u * 8;
  } else {
    int v = u - VOCAB * 16;                 // 4 x 2048 units of weights
    if (v >= 4 * 2048) return;
    int m = v >> 11, loc = v & 2047;
    const float* w = (m == 0) ? w1a : (m == 1) ? w1b : (m == 2) ? w2a : w2b;
    src = w + (size_t)loc * 8;
    dst = wbf + (size_t)v * 8;
  }
  f32x4 a = ((const f32x4*)src)[0], b = ((const f32x4*)src)[1];
  bf16x8 o;
  #pragma unroll
  for (int e = 0; e < 4; ++e) {
    o[e] = (short)f2bf(a[e]);
    o[4 + e] = (short)f2bf(b[e]);
  }
  *(bf16x8*)dst = o;
}

// ---------------------------------------------------------------- bucket build (single kernel)
// count in LDS -> one global atomicAdd per bucket to allocate span -> scatter with LDS ranks
__global__ __launch_bounds__(512) void build_kernel(
    const int* __restrict__ ei, int* __restrict__ gcnt,
    unsigned* __restrict__ eb) {
  __shared__ unsigned cnt[NBKT];
  __shared__ unsigned base[NBKT];
  int t = threadIdx.x, b = blockIdx.x;
  for (int i = t; i < NBKT; i += 512) cnt[i] = 0;
  __syncthreads();
  int ebase = b * EPB2;
  for (int i = t; i < EPB2; i += 512)
    atomicAdd(&cnt[(unsigned)ei[N_EDGES + ebase + i] >> 7], 1u);
  __syncthreads();
  for (int i = t; i < NBKT; i += 512) {
    base[i] = (unsigned)atomicAdd(&gcnt[i], (int)cnt[i]);
    cnt[i] = 0;
  }
  __syncthreads();
  for (int i = t; i < EPB2; i += 512) {
    int sn = ei[ebase + i];
    unsigned d = (unsigned)ei[N_EDGES + ebase + i];
    unsigned bk = d >> 7;
    unsigned r = atomicAdd(&cnt[bk], 1u);
    unsigned pos = base[bk] + r;
    if (pos < CAP)
      eb[(size_t)bk * CAP + pos] = ((d & 127u) << 16) | (unsigned)sn;
  }
}

// ---------------------------------------------------------------- sort + conv1-aggregate (fused)
// per bucket: LDS counting sort by dloc; emit srt16/rowlo/rowhi for conv2;
// then aggregate 128 nodes from the L2-resident emb table using LDS-sorted lists.
__global__ __launch_bounds__(512) void sort_agg1_kernel(
    const unsigned* __restrict__ eb, const int* __restrict__ gcnt,
    const unsigned short* __restrict__ embb, const int* __restrict__ xidx,
    unsigned short* __restrict__ srt16, int* __restrict__ rowlo,
    int* __restrict__ rowhi, unsigned short* __restrict__ xa) {
  __shared__ unsigned stage[CAP];        // 16 KB
  __shared__ unsigned short sorted[CAP]; // 8 KB
  __shared__ unsigned hist[128], cur[128];
  __shared__ unsigned wtot;
  int t = threadIdx.x, bkt = blockIdx.x;
  int cnt = gcnt[bkt];
  if (cnt > CAP) cnt = CAP;
  size_t ebbase = (size_t)bkt * CAP;
  if (t < 128) hist[t] = 0;
  __syncthreads();
  for (int i = t; i < cnt; i += 512) {
    unsigned e = eb[ebbase + i];
    stage[i] = e;
    atomicAdd(&hist[e >> 16], 1u);
  }
  __syncthreads();
  if (t < 128) {                         // exclusive scan of 128 node counters
    int lane = t & 63;
    unsigned v = hist[t], ss = v;
    #pragma unroll
    for (int d = 1; d < 64; d <<= 1) {
      unsigned u = __shfl_up(ss, d, 64);
      if (lane >= d) ss += u;
    }
    if (t == 63) wtot = ss;
    cur[t] = ss - v;                     // wave-local exclusive
  }
  __syncthreads();
  if (t < 128) {
    unsigned e0 = cur[t] + (t >= 64 ? wtot : 0u);
    cur[t] = e0;
    int n = bkt * 128 + t;
    if (n < N_NODES) {
      rowlo[n] = (int)(ebbase + e0);
      rowhi[n] = (int)(ebbase + e0 + hist[t]);
    }
  }
  __syncthreads();
  for (int i = t; i < cnt; i += 512) {
    unsigned e = stage[i];
    unsigned r = atomicAdd(&cur[e >> 16], 1u);
    sorted[r] = (unsigned short)(e & 0xFFFFu);
  }
  __syncthreads();                       // sorted/cur stable from here (read-only below)

  // export sorted src list for conv2
  for (int i = t; i < cnt; i += 512) srt16[ebbase + i] = sorted[i];

  // conv1 aggregation: 32 groups x 16 lanes; group g handles dloc g, g+32, g+64, g+96
  int g = t >> 4, c = t & 15;
  for (int ii = 0; ii < 4; ++ii) {
    int dloc = ii * 32 + g;
    int node = bkt * 128 + dloc;
    if (node >= N_NODES) continue;
    int hi = (int)cur[dloc];
    int lo = hi - (int)hist[dloc];
    bf16x8 sv = *(const bf16x8*)(embb + (size_t)xidx[node] * DIM + c * 8);
    float a[8];
    #pragma unroll
    for (int e = 0; e < 8; ++e) a[e] = bf2f((unsigned short)sv[e]);
    int k = lo;
    for (; k + 8 <= hi; k += 8) {
      bf16x8 w[8];
      #pragma unroll
      for (int q = 0; q < 8; ++q)
        w[q] = *(const bf16x8*)(embb + (size_t)xidx[sorted[k + q]] * DIM + c * 8);
      #pragma unroll
      for (int q = 0; q < 8; ++q)
        #pragma unroll
        for (int e = 0; e < 8; ++e) a[e] += bf2f((unsigned short)w[q][e]);
    }
    for (; k + 2 <= hi; k += 2) {
      bf16x8 w0 = *(const bf16x8*)(embb + (size_t)xidx[sorted[k]] * DIM + c * 8);
      bf16x8 w1 = *(const bf16x8*)(embb + (size_t)xidx[sorted[k + 1]] * DIM + c * 8);
      #pragma unroll
      for (int e = 0; e < 8; ++e)
        a[e] += bf2f((unsigned short)w0[e]) + bf2f((unsigned short)w1[e]);
    }
    if (k < hi) {
      bf16x8 w = *(const bf16x8*)(embb + (size_t)xidx[sorted[k]] * DIM + c * 8);
      #pragma unroll
      for (int e = 0; e < 8; ++e) a[e] += bf2f((unsigned short)w[e]);
    }
    bf16x8 o;
    #pragma unroll
    for (int e = 0; e < 8; ++e) o[e] = (short)f2bf(a[e]);
    *(bf16x8*)(xa + (size_t)node * DIM + c * 8) = o;
  }
}

// ---------------------------------------------------------------- agg (conv2): from node features
__global__ __launch_bounds__(256) void agg_x_kernel(
    const unsigned short* __restrict__ x, const int* __restrict__ rowlo,
    const int* __restrict__ rowhi, const unsigned short* __restrict__ srt16,
    unsigned short* __restrict__ xa) {
  int n = blockIdx.x * 16 + (threadIdx.x >> 4);
  int c = threadIdx.x & 15;
  int lo = rowlo[n], hi = rowhi[n];
  bf16x8 sv = *(const bf16x8*)(x + (size_t)n * DIM + c * 8);
  float a[8];
  #pragma unroll
  for (int e = 0; e < 8; ++e) a[e] = bf2f((unsigned short)sv[e]);
  int k = lo;
  for (; k + 8 <= hi; k += 8) {
    bf16x8 w[8];
    #pragma unroll
    for (int q = 0; q < 8; ++q)
      w[q] = *(const bf16x8*)(x + (size_t)srt16[k + q] * DIM + c * 8);
    #pragma unroll
    for (int q = 0; q < 8; ++q)
      #pragma unroll
      for (int e = 0; e < 8; ++e) a[e] += bf2f((unsigned short)w[q][e]);
  }
  for (; k + 2 <= hi; k += 2) {
    bf16x8 w0 = *(const bf16x8*)(x + (size_t)srt16[k] * DIM + c * 8);
    bf16x8 w1 = *(const bf16x8*)(x + (size_t)srt16[k + 1] * DIM + c * 8);
    #pragma unroll
    for (int e = 0; e < 8; ++e)
      a[e] += bf2f((unsigned short)w0[e]) + bf2f((unsigned short)w1[e]);
  }
  if (k < hi) {
    bf16x8 w = *(const bf16x8*)(x + (size_t)srt16[k] * DIM + c * 8);
    #pragma unroll
    for (int e = 0; e < 8; ++e) a[e] += bf2f((unsigned short)w[e]);
  }
  bf16x8 o;
  #pragma unroll
  for (int e = 0; e < 8; ++e) o[e] = (short)f2bf(a[e]);
  *(bf16x8*)(xa + (size_t)n * DIM + c * 8) = o;
}

// ---------------------------------------------------------------- MLP: 256 thr, 128 nodes (2 halves)
__global__ __launch_bounds__(256) void mlp_mfma_kernel(
    const unsigned short* __restrict__ xa,
    const unsigned short* __restrict__ wabf, const float* __restrict__ ba,
    const unsigned short* __restrict__ wbbf, const float* __restrict__ bb,
    unsigned short* __restrict__ xout) {
  __shared__ short Xs[64 * 128];   // 16 KB, 16B-chunk XOR swizzle (chunk ^= row&7)
  __shared__ short Hs[64 * 128];   // 16 KB
  int t = threadIdx.x;
  int lane = t & 63;
  int w = t >> 6;
  int jq = w * 32;
  int l15 = lane & 15;
  int lg = lane >> 4;

  bf16x8 waf[2][4], wbf[2][4];
  #pragma unroll
  for (int jm = 0; jm < 2; ++jm) {
    int jrow = jq + jm * 16 + l15;
    #pragma unroll
    for (int ks = 0; ks < 4; ++ks) {
      int k0 = ks * 32 + lg * 8;
      waf[jm][ks] = *(const bf16x8*)(wabf + (size_t)jrow * DIM + k0);
      wbf[jm][ks] = *(const bf16x8*)(wbbf + (size_t)jrow * DIM + k0);
    }
  }
  f32x4 ba_r[2], bb_r[2];
  #pragma unroll
  for (int jm = 0; jm < 2; ++jm) {
    ba_r[jm] = *(const f32x4*)(ba + jq + jm * 16 + lg * 4);
    bb_r[jm] = *(const f32x4*)(bb + jq + jm * 16 + lg * 4);
  }

  for (int half = 0; half < 2; ++half) {
    int nbase = blockIdx.x * 128 + half * 64;

    {
      int r = t >> 2;
      int cb = (t & 3) * 4;
      int node = nbase + r;
      #pragma unroll
      for (int i = 0; i < 4; ++i) {
        int chunk = cb + i;
        bf16x8 v = {0, 0, 0, 0, 0, 0, 0, 0};
        if (node < N_NODES)
          v = *(const bf16x8*)(xa + (size_t)node * DIM + chunk * 8);
        *(bf16x8*)&Xs[r * 128 + ((chunk ^ (r & 7)) << 3)] = v;
      }
    }
    __syncthreads();

    #pragma unroll
    for (int nt = 0; nt < 4; ++nt) {
      int rrow = nt * 16 + l15;
      bf16x8 xf[4];
      #pragma unroll
      for (int ks = 0; ks < 4; ++ks) {
        int chunk = ks * 4 + lg;
        xf[ks] = *(const bf16x8*)&Xs[rrow * 128 + ((chunk ^ (rrow & 7)) << 3)];
      }
      #pragma unroll
      for (int jm = 0; jm < 2; ++jm) {
        f32x4 acc = ba_r[jm];
        #pragma unroll
        for (int ks = 0; ks < 4; ++ks)
          acc = __builtin_amdgcn_mfma_f32_16x16x32_bf16(waf[jm][ks], xf[ks], acc, 0, 0, 0);
        int hnode = nt * 16 + l15;
        int cbase = jq + jm * 16 + lg * 4;
        unsigned p0 = (unsigned)f2bf(fmaxf(acc[0], 0.f)) |
                      ((unsigned)f2bf(fmaxf(acc[1], 0.f)) << 16);
        unsigned p1 = (unsigned)f2bf(fmaxf(acc[2], 0.f)) |
                      ((unsigned)f2bf(fmaxf(acc[3], 0.f)) << 16);
        unsigned idx = hnode * 128 + (((cbase >> 3) ^ (hnode & 7)) << 3) + (cbase & 7);
        *(uint2*)&Hs[idx] = make_uint2(p0, p1);
      }
    }
    __syncthreads();

    #pragma unroll
    for (int nt = 0; nt < 4; ++nt) {
      int rrow = nt * 16 + l15;
      bf16x8 hf[4];
      #pragma unroll
      for (int ks = 0; ks < 4; ++ks) {
        int chunk = ks * 4 + lg;
        hf[ks] = *(const bf16x8*)&Hs[rrow * 128 + ((chunk ^ (rrow & 7)) << 3)];
      }
      #pragma unroll
      for (int jm = 0; jm < 2; ++jm) {
        f32x4 acc = bb_r[jm];
        #pragma unroll
        for (int ks = 0; ks < 4; ++ks)
          acc = __builtin_amdgcn_mfma_f32_16x16x32_bf16(wbf[jm][ks], hf[ks], acc, 0, 0, 0);
        int node = nbase + nt * 16 + l15;
        if (node < N_NODES) {
          bf16x4 o;
          #pragma unroll
          for (int e = 0; e < 4; ++e) o[e] = (short)f2bf(fmaxf(acc[e], 0.f));
          *(bf16x4*)(xout + (size_t)node * DIM + jq + jm * 16 + lg * 4) = o;
        }
      }
    }
    __syncthreads();   // protect Xs/Hs before next half
  }
}

// ---------------------------------------------------------------- mean-pool + FC (row-parallel)
#define PP 132
__global__ __launch_bounds__(256) void pool_fc_kernel(
    const unsigned short* __restrict__ x, const int* __restrict__ batch,
    const float* __restrict__ fcw, const float* __restrict__ fcb,
    float* __restrict__ out) {
  int g = blockIdx.x, t = threadIdx.x;
  __shared__ float part[16 * PP];
  __shared__ float pooled[DIM];
  __shared__ int sbound[2];
  if (t < 2) {
    int target = g + t;
    int lo = 0, hi = N_NODES;
    while (lo < hi) {
      int m = (lo + hi) >> 1;
      if (batch[m] < target) lo = m + 1; else hi = m;
    }
    sbound[t] = lo;
  }
  __syncthreads();
  int lo = sbound[0], hi = sbound[1];
  int r = t >> 4, c = t & 15;
  float acc[8] = {0.f, 0.f, 0.f, 0.f, 0.f, 0.f, 0.f, 0.f};
  for (int nn = lo + r; nn < hi; nn += 16) {
    bf16x8 v = *(const bf16x8*)(x + (size_t)nn * DIM + c * 8);
    #pragma unroll
    for (int e = 0; e < 8; ++e) acc[e] += bf2f((unsigned short)v[e]);
  }
  #pragma unroll
  for (int e = 0; e < 8; ++e) part[r * PP + c * 8 + e] = acc[e];
  __syncthreads();
  if (t < DIM) {
    float s = 0.f;
    #pragma unroll
    for (int rr = 0; rr < 16; ++rr) s += part[rr * PP + t];
    pooled[t] = s / fmaxf((float)(hi - lo), 1.0f);
  }
  __syncthreads();
  if (t < ODIM) {
    float a = fcb[t];
    const float* wr = fcw + (size_t)t * DIM;
    #pragma unroll 8
    for (int h = 0; h < DIM; ++h) a += pooled[h] * wr[h];
    out[(size_t)g * ODIM + t] = a;
  }
}

// ---------------------------------------------------------------- launch
extern "C" void kernel_launch(void* const* d_in, const int* in_sizes, int n_in,
                              void* d_out, int out_size, void* d_ws, size_t ws_size,
                              hipStream_t stream) {
  const float* emb  = (const float*)d_in[0];
  const float* w1a  = (const float*)d_in[1];
  const float* b1a  = (const float*)d_in[2];
  const float* w1b  = (const float*)d_in[3];
  const float* b1b  = (const float*)d_in[4];
  const float* w2a  = (const float*)d_in[5];
  const float* b2a  = (const float*)d_in[6];
  const float* w2b  = (const float*)d_in[7];
  const float* b2b  = (const float*)d_in[8];
  const float* fcw  = (const float*)d_in[9];
  const float* fcb  = (const float*)d_in[10];
  const int*   xidx = (const int*)d_in[11];
  const int*   ei   = (const int*)d_in[12];
  const int*   batch= (const int*)d_in[13];
  float* out = (float*)d_out;

  size_t featb = (size_t)N_NODES * DIM * sizeof(unsigned short);  // 12.8 MB
  char* ws = (char*)d_ws;
  unsigned short* B1 = (unsigned short*)ws;             // agg buffer
  unsigned short* B2 = (unsigned short*)(ws + featb);   // conv out
  char* p = ws + 2 * featb;
  unsigned short* embb = (unsigned short*)p;  p += (VOCAB * DIM * 2 + 15) / 16 * 16;
  unsigned short* wbf  = (unsigned short*)p;  p += (4 * DIM * DIM * 2 + 15) / 16 * 16;  // 128 KB
  int* gcnt  = (int*)p;     p += (NBKT * 4 + 15) / 16 * 16;
  int* rowlo = (int*)p;     p += ((size_t)N_NODES * 4 + 15) / 16 * 16;
  int* rowhi = (int*)p;     p += ((size_t)N_NODES * 4 + 15) / 16 * 16;
  unsigned* eb = (unsigned*)p;          p += (size_t)NBKT * CAP * 4;   // 6.4 MB
  unsigned short* srt16 = (unsigned short*)p;                          // 3.2 MB

  const unsigned short* w1abf = wbf;
  const unsigned short* w1bbf = wbf + DIM * DIM;
  const unsigned short* w2abf = wbf + 2 * DIM * DIM;
  const unsigned short* w2bbf = wbf + 3 * DIM * DIM;

  prep_kernel<<<(VOCAB * 16 + 4 * 2048 + 255) / 256, 256, 0, stream>>>(
      emb, w1a, w1b, w2a, w2b, embb, wbf, gcnt);

  // bucket build (count -> span-alloc -> scatter) in ONE kernel
  build_kernel<<<NB2, 512, 0, stream>>>(ei, gcnt, eb);

  // sort buckets + conv1 aggregation fused; emits srt16/rowlo/rowhi for conv2
  sort_agg1_kernel<<<NBKT, 512, 0, stream>>>(eb, gcnt, embb, xidx, srt16, rowlo, rowhi, B1);
  mlp_mfma_kernel<<<(N_NODES + 127) / 128, 256, 0, stream>>>(B1, w1abf, b1a, w1bbf, b1b, B2);

  // conv2: gather from node features, then MLP
  agg_x_kernel<<<N_NODES / 16, 256, 0, stream>>>(B2, rowlo, rowhi, srt16, B1);
  mlp_mfma_kernel<<<(N_NODES + 127) / 128, 256, 0, stream>>>(B1, w2abf, b2a, w2bbf, b2b, B2);

  pool_fc_kernel<<<NGRAPH, 256, 0, stream>>>(B2, batch, fcw, fcb, out);
}